// Round 7
// baseline (639.480 us; speedup 1.0000x reference)
//
#include <hip/hip_runtime.h>
#include <hip/hip_fp16.h>

// ---------------------------------------------------------------------------
// localAE: two GCNConv layers (128->64 encode, 64->128 decode), N=100000,
// E=1.6M.  out[n] = dinv[n] * (hs[n] + sum_{e: dst==n} hs[src_e]) + b
// where hs = (X @ W) * dinv[row],  dinv = rsqrt(1 + indegree).
//
// Round 9: GEMM latency fix, take 2. Round-8 R=4 retile kept gemm at 48us,
// VALUBusy 25%, Occupancy 19%: latency-bound on L3-resident X (FETCH 25MB
// of 51MB; ~3 waves/SIMD can't cover ~500cy L3 hits with 16B/thread in
// flight). Now R=2 (encode TM=64 -> 1563 blocks, decode TM=32 -> 3125
// blocks; LDS-capped 5 blocks/CU = 20 waves/CU reachable) and line-granular
// double-buffered prefetch: superchunks of 16 k (one 64B line/row), next
// line's 4 float4 issued before the current 256-FMA block. Pure f32.
// ---------------------------------------------------------------------------

#define BSHIFT 7                      // 128 nodes per bucket
#define BNODES (1 << BSHIFT)
#define NB_LDS 1024                   // LDS histogram capacity (NB <= 1024)

// P1: partition edges into buckets by dst>>BSHIFT, packed (src<<BSHIFT)|dloc.
// One global atomic per (block,bucket) instead of per edge (fabric-RMW wall).
__global__ __launch_bounds__(1024)
void part_kernel(const int* __restrict__ src, const int* __restrict__ dst,
                 int E, int NB, int* __restrict__ gcur, int* __restrict__ gbuf,
                 int BSTRIDE)
{
    __shared__ int hist[NB_LDS];
    __shared__ int bbase[NB_LDS];
    const int tid = threadIdx.x;
    for (int i = tid; i < NB; i += 1024) hist[i] = 0;
    __syncthreads();

    const int base = (blockIdx.x * 1024 + tid) * 4;
    int bk[4], lp[4], pk[4];
    int nv = 0;
    if (base + 4 <= E) {
        const int4 d4 = *reinterpret_cast<const int4*>(dst + base);
        const int4 s4 = *reinterpret_cast<const int4*>(src + base);
        nv = 4;
        #pragma unroll
        for (int k = 0; k < 4; ++k) {
            const int d = (&d4.x)[k];
            bk[k] = d >> BSHIFT;
            pk[k] = ((&s4.x)[k] << BSHIFT) | (d & (BNODES - 1));
            lp[k] = atomicAdd(&hist[bk[k]], 1);
        }
    } else {
        for (int k = 0; base + k < E && k < 4; ++k) {
            const int d = dst[base + k];
            bk[nv] = d >> BSHIFT;
            pk[nv] = (src[base + k] << BSHIFT) | (d & (BNODES - 1));
            lp[nv] = atomicAdd(&hist[bk[nv]], 1);
            ++nv;
        }
    }
    __syncthreads();
    for (int i = tid; i < NB; i += 1024) {
        const int c = hist[i];
        bbase[i] = c ? atomicAdd(&gcur[i], c) : 0;   // one device atomic per (block,bucket)
    }
    __syncthreads();
    for (int k = 0; k < nv; ++k) {
        const int pos = bbase[bk[k]] + lp[k];
        if (pos < BSTRIDE) gbuf[(size_t)bk[k] * BSTRIDE + pos] = pk[k];
    }
}

// P2: per bucket (128 nodes), slot edges into CSR rows via LDS cursors
// (zero fabric RMW); CSR writes confined to a 32KB region -> merge in L2.
// Degree count + dinv fused.
__global__ __launch_bounds__(256)
void csr_kernel(const int* __restrict__ gcur, const int* __restrict__ gbuf,
                int BSTRIDE, int* __restrict__ csr, int cap,
                int* __restrict__ cnt, float* __restrict__ dinv, int M)
{
    __shared__ int cur[BNODES];
    const int tid = threadIdx.x;
    const int b   = blockIdx.x;
    if (tid < BNODES) cur[tid] = 0;
    __syncthreads();

    int nb = gcur[b];
    if (nb > BSTRIDE) nb = BSTRIDE;
    const int* __restrict__ buf = gbuf + (size_t)b * BSTRIDE;
    const int n0 = b << BSHIFT;

    for (int i = tid; i < nb; i += 256) {
        const int p = buf[i];
        const int d = p & (BNODES - 1);
        const int s = p >> BSHIFT;
        const int lpos = atomicAdd(&cur[d], 1);        // LDS atomic
        if (lpos < cap) csr[(size_t)(n0 + d) * cap + lpos] = s;
    }
    __syncthreads();
    const int n = n0 + tid;
    if (tid < BNODES && n < M) {
        const int c = cur[tid];
        cnt[n]  = c;                                   // true in-degree
        dinv[n] = rsqrtf((float)c + 1.0f);             // +1 self-loop
    }
}

// Register-blocked GEMM: out[m,:] = (X[m,:] @ W) * dinv[m] (+ bias).
// 256 threads as CG col-groups x RG row-groups; each thread computes an
// R-row x 8-col output tile. W staged in LDS (32KB, broadcast b128 reads);
// X read from global through L1/L3 in 64B-line superchunks (16 k), next
// line double-buffered in registers so each miss is issued one full
// 256-FMA block ahead.
template<int K, int N, int CG, int R, bool HOUT>
__global__ __launch_bounds__(256)
void gemm_rb(const float* __restrict__ X, const float* __restrict__ W,
             const float* __restrict__ dinv, const float* __restrict__ bias,
             float* __restrict__ out, __half* __restrict__ outh, int M)
{
    constexpr int RG = 256 / CG;
    constexpr int TM = RG * R;
    __shared__ float Ws[K * N];

    const int tid = threadIdx.x;
    for (int i = tid; i < K * N / 4; i += 256)
        reinterpret_cast<float4*>(Ws)[i] = reinterpret_cast<const float4*>(W)[i];
    __syncthreads();

    const int cg   = tid % CG;
    const int rg   = tid / CG;
    const int c0   = cg * 8;
    const int row0 = blockIdx.x * TM + rg * R;

    float acc[R][8];
    #pragma unroll
    for (int r = 0; r < R; ++r)
        #pragma unroll
        for (int c = 0; c < 8; ++c) acc[r][c] = 0.f;

    const float* xp[R];
    #pragma unroll
    for (int r = 0; r < R; ++r) {
        int rr = row0 + r;
        if (rr >= M) rr = M - 1;                  // clamp loads; stores guarded
        xp[r] = X + (size_t)rr * K;
    }

    float4 xv[R][4];                              // current 64B line per row
    #pragma unroll
    for (int r = 0; r < R; ++r)
        #pragma unroll
        for (int q = 0; q < 4; ++q)
            xv[r][q] = *reinterpret_cast<const float4*>(xp[r] + q * 4);

    for (int k0 = 0; k0 < K; k0 += 16) {
        float4 xn[R][4];
        const bool more = (k0 + 16 < K);
        if (more) {
            #pragma unroll
            for (int r = 0; r < R; ++r)
                #pragma unroll
                for (int q = 0; q < 4; ++q)
                    xn[r][q] = *reinterpret_cast<const float4*>(xp[r] + k0 + 16 + q * 4);
        }
        #pragma unroll
        for (int q = 0; q < 4; ++q) {
            #pragma unroll
            for (int kk = 0; kk < 4; ++kk) {
                const int k = k0 + q * 4 + kk;
                const float4 w0 = *reinterpret_cast<const float4*>(&Ws[k * N + c0]);
                const float4 w1 = *reinterpret_cast<const float4*>(&Ws[k * N + c0 + 4]);
                #pragma unroll
                for (int r = 0; r < R; ++r) {
                    const float xs = (&xv[r][q].x)[kk];
                    acc[r][0] += xs * w0.x; acc[r][1] += xs * w0.y;
                    acc[r][2] += xs * w0.z; acc[r][3] += xs * w0.w;
                    acc[r][4] += xs * w1.x; acc[r][5] += xs * w1.y;
                    acc[r][6] += xs * w1.z; acc[r][7] += xs * w1.w;
                }
            }
        }
        if (more) {
            #pragma unroll
            for (int r = 0; r < R; ++r)
                #pragma unroll
                for (int q = 0; q < 4; ++q)
                    xv[r][q] = xn[r][q];
        }
    }

    float4 bv0 = make_float4(0.f, 0.f, 0.f, 0.f);
    float4 bv1 = make_float4(0.f, 0.f, 0.f, 0.f);
    if (bias) {
        bv0 = *reinterpret_cast<const float4*>(&bias[c0]);
        bv1 = *reinterpret_cast<const float4*>(&bias[c0 + 4]);
    }

    #pragma unroll
    for (int r = 0; r < R; ++r) {
        const int gr = row0 + r;
        if (gr < M) {
            const float d = dinv[gr];
            if constexpr (HOUT) {
                union { __half2 h2[4]; uint4 u; } pk;
                pk.h2[0] = __floats2half2_rn(acc[r][0] * d, acc[r][1] * d);
                pk.h2[1] = __floats2half2_rn(acc[r][2] * d, acc[r][3] * d);
                pk.h2[2] = __floats2half2_rn(acc[r][4] * d, acc[r][5] * d);
                pk.h2[3] = __floats2half2_rn(acc[r][6] * d, acc[r][7] * d);
                *reinterpret_cast<uint4*>(&outh[(size_t)gr * N + c0]) = pk.u;
            } else {
                float4 v0, v1;
                v0.x = acc[r][0] * d + bv0.x; v0.y = acc[r][1] * d + bv0.y;
                v0.z = acc[r][2] * d + bv0.z; v0.w = acc[r][3] * d + bv0.w;
                v1.x = acc[r][4] * d + bv1.x; v1.y = acc[r][5] * d + bv1.y;
                v1.z = acc[r][6] * d + bv1.z; v1.w = acc[r][7] * d + bv1.w;
                *reinterpret_cast<float4*>(&out[(size_t)gr * N + c0])     = v0;
                *reinterpret_cast<float4*>(&out[(size_t)gr * N + c0 + 4]) = v1;
            }
        }
    }
}

// Wave-per-node gather aggregation over 64-dim fp16 rows (1 half/lane,
// 128B/wave-gather = one cache line). f32 accumulate. Edge-index loads are
// wave-uniform (n pinned to SGPR) -> scalar loads. Unroll 16 ~ avg degree.
//  FIRST=true : hsh = hs1;  emb[n] = acc*dinv[n] + bias (f32 out)
//               and ghalf[n] = emb[n]*dinv[n] (fp16 out, feeds agg2)
//  FIRST=false: hsh = g;    out[n] = acc (f32, feeds decode GEMM)
template<bool FIRST>
__global__ __launch_bounds__(256)
void gcn_agg(const __half* __restrict__ hsh, const int* __restrict__ csr,
             const int* __restrict__ cnt, const float* __restrict__ dinv,
             const float* __restrict__ bias, float* __restrict__ outf,
             __half* __restrict__ outh, int M, int cap)
{
    const int lane = threadIdx.x & 63;
    int n = (blockIdx.x * 256 + threadIdx.x) >> 6;
    if (n >= M) return;
    n = __builtin_amdgcn_readfirstlane(n);
    int deg = cnt[n];
    if (deg > cap) deg = cap;
    const int* __restrict__ lst = csr + (size_t)n * cap;

    float acc = __half2float(hsh[(size_t)n * 64 + lane]);

    int j = 0;
    for (; j + 16 <= deg; j += 16) {
        int   s[16];
        float v[16];
        #pragma unroll
        for (int k = 0; k < 16; ++k) s[k] = lst[j + k];
        #pragma unroll
        for (int k = 0; k < 16; ++k) v[k] = __half2float(hsh[(size_t)s[k] * 64 + lane]);
        float t = 0.f;
        #pragma unroll
        for (int k = 0; k < 16; ++k) t += v[k];
        acc += t;
    }
    for (; j + 4 <= deg; j += 4) {
        const int s0 = lst[j], s1 = lst[j + 1], s2 = lst[j + 2], s3 = lst[j + 3];
        const float v0 = __half2float(hsh[(size_t)s0 * 64 + lane]);
        const float v1 = __half2float(hsh[(size_t)s1 * 64 + lane]);
        const float v2 = __half2float(hsh[(size_t)s2 * 64 + lane]);
        const float v3 = __half2float(hsh[(size_t)s3 * 64 + lane]);
        acc += (v0 + v1) + (v2 + v3);
    }
    for (; j < deg; ++j) acc += __half2float(hsh[(size_t)lst[j] * 64 + lane]);

    if constexpr (FIRST) {
        const float dv = dinv[n];
        const float e  = acc * dv + bias[lane];
        outf[(size_t)n * 64 + lane] = e;                       // emb (f32 output)
        outh[(size_t)n * 64 + lane] = __float2half_rn(e * dv); // g = emb*dinv (fp16)
    } else {
        outf[(size_t)n * 64 + lane] = acc;                     // agg2 (f32)
    }
}

extern "C" void kernel_launch(void* const* d_in, const int* in_sizes, int n_in,
                              void* d_out, int out_size, void* d_ws, size_t ws_size,
                              hipStream_t stream)
{
    const float* x    = (const float*)d_in[0];   // [M,128]
    const int*   ei   = (const int*)  d_in[1];   // [2,E]
    const float* Wenc = (const float*)d_in[2];   // [128,64]
    const float* benc = (const float*)d_in[3];   // [64]
    const float* Wdec = (const float*)d_in[4];   // [64,128]
    const float* bdec = (const float*)d_in[5];   // [128]

    const int M = in_sizes[0] / 128;             // 100000
    const int E = in_sizes[1] / 2;               // 1600000
    const int* src  = ei;
    const int* dstv = ei + E;

    float* emb   = (float*)d_out;                       // [M,64]
    float* recon = (float*)d_out + (size_t)M * 64;      // [M,128]

    const int NB      = (M + BNODES - 1) >> BSHIFT;     // 782 buckets
    const int BSTRIDE = 3072;                           // mean 2046, +22 sigma

    // workspace layout (int units):
    //   [0,       M*32)    hs1h  (layer-1 pre-agg, fp16, M*64 halves)
    //   [M*32,    M*64)    ghalf (g = emb*dinv, fp16, M*64 halves)
    //   [M*64,    M*128)   gbuf (P1 output, 2.4M ints) UNION agg2 (f32 M*64)
    //   [M*128,   M*129)   cnt  (in-degree)
    //   [M*129,   M*130)   dinv (f32)
    //   [M*130,   +1024)   gcur (bucket counters, padded)
    //   [M*130+1024, ...)  csr  (M*cap)
    __half* hs1h  = (__half*)d_ws;
    __half* ghalf = (__half*)((int*)d_ws + (size_t)M * 32);
    int*    gbuf  = (int*)d_ws + (size_t)M * 64;
    float*  agg2  = (float*)((int*)d_ws + (size_t)M * 64);
    int*    cnt   = (int*)d_ws + (size_t)M * 128;
    float*  dinv  = (float*)((int*)d_ws + (size_t)M * 129);
    int*    gcur  = (int*)d_ws + (size_t)M * 130;
    int*    csr   = (int*)d_ws + (size_t)M * 130 + 1024;

    const size_t used = ((size_t)M * 130 + 1024) * 4;
    int cap = 64;                                        // Poisson(16): P(deg>64) ~ 1e-50
    const size_t avail = (ws_size > used) ? (ws_size - used) / ((size_t)M * 4) : 0;
    if ((size_t)cap > avail) cap = (int)avail;

    hipMemsetAsync(gcur, 0, 1024 * sizeof(int), stream);

    // ---- CSR build: partition (4096 edges/block) then per-bucket slotting ----
    part_kernel<<<(E + 4095) / 4096, 1024, 0, stream>>>(src, dstv, E, NB, gcur, gbuf, BSTRIDE);
    csr_kernel<<<NB, 256, 0, stream>>>(gcur, gbuf, BSTRIDE, csr, cap, cnt, dinv, M);

    const int aggBlocks = (M + 3) / 4;   // 4 waves (nodes) per 256-thread block

    // ---- layer 1: encode 128 -> 64 ----
    // CG=8 x R=2: tile 64 rows x 64 cols, 1563 blocks (5 blocks/CU LDS-capped)
    gemm_rb<128, 64, 8, 2, true><<<(M + 63) / 64, 256, 0, stream>>>(
        x, Wenc, dinv, nullptr, nullptr, hs1h, M);
    gcn_agg<true><<<aggBlocks, 256, 0, stream>>>(
        hs1h, csr, cnt, dinv, benc, emb, ghalf, M, cap);

    // ---- layer 2: decode 64 -> 128 (aggregate in 64-dim, then GEMM) ----
    gcn_agg<false><<<aggBlocks, 256, 0, stream>>>(
        ghalf, csr, cnt, nullptr, nullptr, agg2, nullptr, M, cap);
    // CG=16 x R=2: tile 32 rows x 128 cols, 3125 blocks (5 blocks/CU LDS-capped)
    gemm_rb<64, 128, 16, 2, false><<<(M + 31) / 32, 256, 0, stream>>>(
        agg2, Wdec, dinv, bdec, recon, nullptr, M);
}

// Round 8
// 313.253 us; speedup vs baseline: 2.0414x; 2.0414x over previous
//
#include <hip/hip_runtime.h>
#include <hip/hip_fp16.h>

// ---------------------------------------------------------------------------
// localAE: two GCNConv layers (128->64 encode, 64->128 decode), N=100000,
// E=1.6M.  out[n] = dinv[n] * (hs[n] + sum_{e: dst==n} hs[src_e]) + b
// where hs = (X @ W) * dinv[row],  dinv = rsqrt(1 + indegree).
//
// Round 10: (a) encode GEMM reverted to the round-6 proven config (R=4,
// 1-chunk reg prefetch; round-7's R=2+superchunk spilled: VGPR 256, 1GB
// scratch traffic, 390us). (b) decode GEMM fused into agg2: each wave
// gathers 8 nodes (acc 1 VGPR/node/lane), stages them in LDS, then matvecs
// against LDS-staged Wdec. 8-node batching amortizes Wdec LDS reads to
// 4KB/node (~6us chip-wide); lane owns cols (2l,2l+1) -> no cross-lane
// reduce, coalesced float2 stores. Removes the 46us gemm2 dispatch and
// agg2's 25.6MB write+read. f32 matvec, same k-order -> reassoc-only noise.
// ---------------------------------------------------------------------------

#define BSHIFT 7                      // 128 nodes per bucket
#define BNODES (1 << BSHIFT)
#define NB_LDS 1024                   // LDS histogram capacity (NB <= 1024)

// P1: partition edges into buckets by dst>>BSHIFT, packed (src<<BSHIFT)|dloc.
// One global atomic per (block,bucket) instead of per edge (fabric-RMW wall).
__global__ __launch_bounds__(1024)
void part_kernel(const int* __restrict__ src, const int* __restrict__ dst,
                 int E, int NB, int* __restrict__ gcur, int* __restrict__ gbuf,
                 int BSTRIDE)
{
    __shared__ int hist[NB_LDS];
    __shared__ int bbase[NB_LDS];
    const int tid = threadIdx.x;
    for (int i = tid; i < NB; i += 1024) hist[i] = 0;
    __syncthreads();

    const int base = (blockIdx.x * 1024 + tid) * 4;
    int bk[4], lp[4], pk[4];
    int nv = 0;
    if (base + 4 <= E) {
        const int4 d4 = *reinterpret_cast<const int4*>(dst + base);
        const int4 s4 = *reinterpret_cast<const int4*>(src + base);
        nv = 4;
        #pragma unroll
        for (int k = 0; k < 4; ++k) {
            const int d = (&d4.x)[k];
            bk[k] = d >> BSHIFT;
            pk[k] = ((&s4.x)[k] << BSHIFT) | (d & (BNODES - 1));
            lp[k] = atomicAdd(&hist[bk[k]], 1);
        }
    } else {
        for (int k = 0; base + k < E && k < 4; ++k) {
            const int d = dst[base + k];
            bk[nv] = d >> BSHIFT;
            pk[nv] = (src[base + k] << BSHIFT) | (d & (BNODES - 1));
            lp[nv] = atomicAdd(&hist[bk[nv]], 1);
            ++nv;
        }
    }
    __syncthreads();
    for (int i = tid; i < NB; i += 1024) {
        const int c = hist[i];
        bbase[i] = c ? atomicAdd(&gcur[i], c) : 0;   // one device atomic per (block,bucket)
    }
    __syncthreads();
    for (int k = 0; k < nv; ++k) {
        const int pos = bbase[bk[k]] + lp[k];
        if (pos < BSTRIDE) gbuf[(size_t)bk[k] * BSTRIDE + pos] = pk[k];
    }
}

// P2: per bucket (128 nodes), slot edges into CSR rows via LDS cursors
// (zero fabric RMW); CSR writes confined to a 32KB region -> merge in L2.
// Degree count + dinv fused.
__global__ __launch_bounds__(256)
void csr_kernel(const int* __restrict__ gcur, const int* __restrict__ gbuf,
                int BSTRIDE, int* __restrict__ csr, int cap,
                int* __restrict__ cnt, float* __restrict__ dinv, int M)
{
    __shared__ int cur[BNODES];
    const int tid = threadIdx.x;
    const int b   = blockIdx.x;
    if (tid < BNODES) cur[tid] = 0;
    __syncthreads();

    int nb = gcur[b];
    if (nb > BSTRIDE) nb = BSTRIDE;
    const int* __restrict__ buf = gbuf + (size_t)b * BSTRIDE;
    const int n0 = b << BSHIFT;

    for (int i = tid; i < nb; i += 256) {
        const int p = buf[i];
        const int d = p & (BNODES - 1);
        const int s = p >> BSHIFT;
        const int lpos = atomicAdd(&cur[d], 1);        // LDS atomic
        if (lpos < cap) csr[(size_t)(n0 + d) * cap + lpos] = s;
    }
    __syncthreads();
    const int n = n0 + tid;
    if (tid < BNODES && n < M) {
        const int c = cur[tid];
        cnt[n]  = c;                                   // true in-degree
        dinv[n] = rsqrtf((float)c + 1.0f);             // +1 self-loop
    }
}

// Register-blocked GEMM (round-6 proven): out[m,:] = (X[m,:] @ W)*dinv[m].
// 256 threads as CG col-groups x RG row-groups; R rows x 8 cols per thread.
// W in LDS (32KB, broadcast b128); X from global through L1, next 4-k chunk
// prefetched into registers. HOUT packs 8 halves -> one 16B store.
template<int K, int N, int CG, int R, bool HOUT>
__global__ __launch_bounds__(256)
void gemm_rb(const float* __restrict__ X, const float* __restrict__ W,
             const float* __restrict__ dinv, const float* __restrict__ bias,
             float* __restrict__ out, __half* __restrict__ outh, int M)
{
    constexpr int RG = 256 / CG;
    constexpr int TM = RG * R;
    __shared__ float Ws[K * N];

    const int tid = threadIdx.x;
    for (int i = tid; i < K * N / 4; i += 256)
        reinterpret_cast<float4*>(Ws)[i] = reinterpret_cast<const float4*>(W)[i];
    __syncthreads();

    const int cg   = tid % CG;
    const int rg   = tid / CG;
    const int c0   = cg * 8;
    const int row0 = blockIdx.x * TM + rg * R;

    float acc[R][8];
    #pragma unroll
    for (int r = 0; r < R; ++r)
        #pragma unroll
        for (int c = 0; c < 8; ++c) acc[r][c] = 0.f;

    const float* xp[R];
    #pragma unroll
    for (int r = 0; r < R; ++r) {
        int rr = row0 + r;
        if (rr >= M) rr = M - 1;                  // clamp loads; stores guarded
        xp[r] = X + (size_t)rr * K;
    }

    float4 xv[R];
    #pragma unroll
    for (int r = 0; r < R; ++r) xv[r] = *reinterpret_cast<const float4*>(xp[r]);

    for (int k = 0; k < K; k += 4) {
        float4 xn[R];
        const bool more = (k + 4 < K);
        if (more) {
            #pragma unroll
            for (int r = 0; r < R; ++r)
                xn[r] = *reinterpret_cast<const float4*>(xp[r] + k + 4);
        }
        #pragma unroll
        for (int kk = 0; kk < 4; ++kk) {
            const float4 w0 = *reinterpret_cast<const float4*>(&Ws[(k + kk) * N + c0]);
            const float4 w1 = *reinterpret_cast<const float4*>(&Ws[(k + kk) * N + c0 + 4]);
            #pragma unroll
            for (int r = 0; r < R; ++r) {
                const float xs = (&xv[r].x)[kk];
                acc[r][0] += xs * w0.x; acc[r][1] += xs * w0.y;
                acc[r][2] += xs * w0.z; acc[r][3] += xs * w0.w;
                acc[r][4] += xs * w1.x; acc[r][5] += xs * w1.y;
                acc[r][6] += xs * w1.z; acc[r][7] += xs * w1.w;
            }
        }
        if (more) {
            #pragma unroll
            for (int r = 0; r < R; ++r) xv[r] = xn[r];
        }
    }

    #pragma unroll
    for (int r = 0; r < R; ++r) {
        const int gr = row0 + r;
        if (gr < M) {
            const float d = dinv[gr];
            if constexpr (HOUT) {
                union { __half2 h2[4]; uint4 u; } pk;
                pk.h2[0] = __floats2half2_rn(acc[r][0] * d, acc[r][1] * d);
                pk.h2[1] = __floats2half2_rn(acc[r][2] * d, acc[r][3] * d);
                pk.h2[2] = __floats2half2_rn(acc[r][4] * d, acc[r][5] * d);
                pk.h2[3] = __floats2half2_rn(acc[r][6] * d, acc[r][7] * d);
                *reinterpret_cast<uint4*>(&outh[(size_t)gr * N + c0]) = pk.u;
            } else {
                float4 bv0 = *reinterpret_cast<const float4*>(&bias[c0]);
                float4 bv1 = *reinterpret_cast<const float4*>(&bias[c0 + 4]);
                float4 v0, v1;
                v0.x = acc[r][0] * d + bv0.x; v0.y = acc[r][1] * d + bv0.y;
                v0.z = acc[r][2] * d + bv0.z; v0.w = acc[r][3] * d + bv0.w;
                v1.x = acc[r][4] * d + bv1.x; v1.y = acc[r][5] * d + bv1.y;
                v1.z = acc[r][6] * d + bv1.z; v1.w = acc[r][7] * d + bv1.w;
                *reinterpret_cast<float4*>(&out[(size_t)gr * N + c0])     = v0;
                *reinterpret_cast<float4*>(&out[(size_t)gr * N + c0 + 4]) = v1;
            }
        }
    }
}

// Layer-1 aggregation (wave per node, 4 nodes/block):
//   emb[n]   = acc*dinv[n] + bias   (f32)
//   ghalf[n] = emb[n]*dinv[n]       (fp16, feeds the fused decode kernel)
__global__ __launch_bounds__(256)
void gcn_agg1(const __half* __restrict__ hsh, const int* __restrict__ csr,
              const int* __restrict__ cnt, const float* __restrict__ dinv,
              const float* __restrict__ bias, float* __restrict__ outf,
              __half* __restrict__ outh, int M, int cap)
{
    const int lane = threadIdx.x & 63;
    int n = (blockIdx.x * 256 + threadIdx.x) >> 6;
    if (n >= M) return;
    n = __builtin_amdgcn_readfirstlane(n);
    int deg = cnt[n];
    if (deg > cap) deg = cap;
    const int* __restrict__ lst = csr + (size_t)n * cap;

    float acc = __half2float(hsh[(size_t)n * 64 + lane]);

    int j = 0;
    for (; j + 16 <= deg; j += 16) {
        int   s[16];
        float v[16];
        #pragma unroll
        for (int k = 0; k < 16; ++k) s[k] = lst[j + k];
        #pragma unroll
        for (int k = 0; k < 16; ++k) v[k] = __half2float(hsh[(size_t)s[k] * 64 + lane]);
        float t = 0.f;
        #pragma unroll
        for (int k = 0; k < 16; ++k) t += v[k];
        acc += t;
    }
    for (; j + 4 <= deg; j += 4) {
        const int s0 = lst[j], s1 = lst[j + 1], s2 = lst[j + 2], s3 = lst[j + 3];
        const float v0 = __half2float(hsh[(size_t)s0 * 64 + lane]);
        const float v1 = __half2float(hsh[(size_t)s1 * 64 + lane]);
        const float v2 = __half2float(hsh[(size_t)s2 * 64 + lane]);
        const float v3 = __half2float(hsh[(size_t)s3 * 64 + lane]);
        acc += (v0 + v1) + (v2 + v3);
    }
    for (; j < deg; ++j) acc += __half2float(hsh[(size_t)lst[j] * 64 + lane]);

    const float dv = dinv[n];
    const float e  = acc * dv + bias[lane];
    outf[(size_t)n * 64 + lane] = e;                       // emb (f32 output)
    outh[(size_t)n * 64 + lane] = __float2half_rn(e * dv); // g = emb*dinv (fp16)
}

// Fused layer-2 aggregation + decode GEMM.
// Block = 256 thr = 4 waves; each wave gathers NB8=8 nodes (64-dim fp16
// g-rows, f32 acc: 1 VGPR/node/lane), transposes them into LDS, then
// matvecs all 8 against LDS-staged Wdec:
//   recon[n][c] = dinv[n] * sum_k acc_n[k]*Wdec[k][c] + bdec[c]
// Lane owns cols (2*lane, 2*lane+1): Wdec b64 reads (4-way conflict, 1.58x),
// acc b128 broadcasts (free), coalesced float2 stores, no cross-lane reduce.
// 8-node batching amortizes Wdec LDS traffic to 4KB/node.
__global__ __launch_bounds__(256)
void agg2_dec(const __half* __restrict__ ghalf, const int* __restrict__ csr,
              const int* __restrict__ cnt, const float* __restrict__ dinv,
              const float* __restrict__ Wdec, const float* __restrict__ bdec,
              float* __restrict__ recon, int M, int cap)
{
    __shared__ float Wl[64 * 128];          // 32 KB
    __shared__ float accb[4][64][8];        // 8 KB: [wave][k][node]

    const int tid  = threadIdx.x;
    const int lane = tid & 63;
    const int wid  = tid >> 6;

    for (int i = tid; i < 64 * 128 / 4; i += 256)
        reinterpret_cast<float4*>(Wl)[i] = reinterpret_cast<const float4*>(Wdec)[i];
    __syncthreads();

    const int nbase = (blockIdx.x * 4 + wid) * 8;

    // ---- gather 8 nodes ----
    float acc[8];
    #pragma unroll
    for (int i = 0; i < 8; ++i) {
        int n = nbase + i;
        if (n >= M) n = M - 1;                 // M=100000 is divisible by 32; safety only
        n = __builtin_amdgcn_readfirstlane(n);
        int deg = cnt[n];
        if (deg > cap) deg = cap;
        const int* __restrict__ lst = csr + (size_t)n * cap;

        float a = __half2float(ghalf[(size_t)n * 64 + lane]);
        int j = 0;
        for (; j + 16 <= deg; j += 16) {
            int   s[16];
            float v[16];
            #pragma unroll
            for (int k = 0; k < 16; ++k) s[k] = lst[j + k];
            #pragma unroll
            for (int k = 0; k < 16; ++k) v[k] = __half2float(ghalf[(size_t)s[k] * 64 + lane]);
            float t = 0.f;
            #pragma unroll
            for (int k = 0; k < 16; ++k) t += v[k];
            a += t;
        }
        for (; j + 4 <= deg; j += 4) {
            const int s0 = lst[j], s1 = lst[j + 1], s2 = lst[j + 2], s3 = lst[j + 3];
            const float v0 = __half2float(ghalf[(size_t)s0 * 64 + lane]);
            const float v1 = __half2float(ghalf[(size_t)s1 * 64 + lane]);
            const float v2 = __half2float(ghalf[(size_t)s2 * 64 + lane]);
            const float v3 = __half2float(ghalf[(size_t)s3 * 64 + lane]);
            a += (v0 + v1) + (v2 + v3);
        }
        for (; j < deg; ++j) a += __half2float(ghalf[(size_t)lst[j] * 64 + lane]);
        acc[i] = a;
    }

    // ---- transpose accs into LDS: accb[wid][k=lane][i] ----
    {
        float4 t0 = make_float4(acc[0], acc[1], acc[2], acc[3]);
        float4 t1 = make_float4(acc[4], acc[5], acc[6], acc[7]);
        *reinterpret_cast<float4*>(&accb[wid][lane][0]) = t0;
        *reinterpret_cast<float4*>(&accb[wid][lane][4]) = t1;
    }
    // same-wave cross-lane LDS write->read: explicit fence (rule #18)
    asm volatile("s_waitcnt lgkmcnt(0)" ::: "memory");
    __builtin_amdgcn_sched_barrier(0);

    // ---- matvec: lane owns cols (2*lane, 2*lane+1) ----
    float p0[8], p1[8];
    #pragma unroll
    for (int i = 0; i < 8; ++i) { p0[i] = 0.f; p1[i] = 0.f; }

    #pragma unroll 4
    for (int k = 0; k < 64; ++k) {
        const float2 wv = *reinterpret_cast<const float2*>(&Wl[k * 128 + lane * 2]);
        const float4 a0 = *reinterpret_cast<const float4*>(&accb[wid][k][0]);
        const float4 a1 = *reinterpret_cast<const float4*>(&accb[wid][k][4]);
        p0[0] += a0.x * wv.x; p1[0] += a0.x * wv.y;
        p0[1] += a0.y * wv.x; p1[1] += a0.y * wv.y;
        p0[2] += a0.z * wv.x; p1[2] += a0.z * wv.y;
        p0[3] += a0.w * wv.x; p1[3] += a0.w * wv.y;
        p0[4] += a1.x * wv.x; p1[4] += a1.x * wv.y;
        p0[5] += a1.y * wv.x; p1[5] += a1.y * wv.y;
        p0[6] += a1.z * wv.x; p1[6] += a1.z * wv.y;
        p0[7] += a1.w * wv.x; p1[7] += a1.w * wv.y;
    }

    const float2 b2 = reinterpret_cast<const float2*>(bdec)[lane];
    #pragma unroll
    for (int i = 0; i < 8; ++i) {
        const int n = nbase + i;
        if (n < M) {
            const float dv = dinv[n];
            float2 o;
            o.x = p0[i] * dv + b2.x;
            o.y = p1[i] * dv + b2.y;
            *reinterpret_cast<float2*>(&recon[(size_t)n * 128 + lane * 2]) = o;
        }
    }
}

extern "C" void kernel_launch(void* const* d_in, const int* in_sizes, int n_in,
                              void* d_out, int out_size, void* d_ws, size_t ws_size,
                              hipStream_t stream)
{
    const float* x    = (const float*)d_in[0];   // [M,128]
    const int*   ei   = (const int*)  d_in[1];   // [2,E]
    const float* Wenc = (const float*)d_in[2];   // [128,64]
    const float* benc = (const float*)d_in[3];   // [64]
    const float* Wdec = (const float*)d_in[4];   // [64,128]
    const float* bdec = (const float*)d_in[5];   // [128]

    const int M = in_sizes[0] / 128;             // 100000
    const int E = in_sizes[1] / 2;               // 1600000
    const int* src  = ei;
    const int* dstv = ei + E;

    float* emb   = (float*)d_out;                       // [M,64]
    float* recon = (float*)d_out + (size_t)M * 64;      // [M,128]

    const int NB      = (M + BNODES - 1) >> BSHIFT;     // 782 buckets
    const int BSTRIDE = 3072;                           // mean 2046, +22 sigma

    // workspace layout (int units):
    //   [0,       M*32)    hs1h  (layer-1 pre-agg, fp16, M*64 halves)
    //   [M*32,    M*64)    ghalf (g = emb*dinv, fp16, M*64 halves)
    //   [M*64,    M*128)   gbuf (P1 output, 2.4M ints)
    //   [M*128,   M*129)   cnt  (in-degree)
    //   [M*129,   M*130)   dinv (f32)
    //   [M*130,   +1024)   gcur (bucket counters, padded)
    //   [M*130+1024, ...)  csr  (M*cap)
    __half* hs1h  = (__half*)d_ws;
    __half* ghalf = (__half*)((int*)d_ws + (size_t)M * 32);
    int*    gbuf  = (int*)d_ws + (size_t)M * 64;
    int*    cnt   = (int*)d_ws + (size_t)M * 128;
    float*  dinv  = (float*)((int*)d_ws + (size_t)M * 129);
    int*    gcur  = (int*)d_ws + (size_t)M * 130;
    int*    csr   = (int*)d_ws + (size_t)M * 130 + 1024;

    const size_t used = ((size_t)M * 130 + 1024) * 4;
    int cap = 64;                                        // Poisson(16): P(deg>64) ~ 1e-50
    const size_t avail = (ws_size > used) ? (ws_size - used) / ((size_t)M * 4) : 0;
    if ((size_t)cap > avail) cap = (int)avail;

    hipMemsetAsync(gcur, 0, 1024 * sizeof(int), stream);

    // ---- CSR build: partition (4096 edges/block) then per-bucket slotting ----
    part_kernel<<<(E + 4095) / 4096, 1024, 0, stream>>>(src, dstv, E, NB, gcur, gbuf, BSTRIDE);
    csr_kernel<<<NB, 256, 0, stream>>>(gcur, gbuf, BSTRIDE, csr, cap, cnt, dinv, M);

    // ---- layer 1: encode 128 -> 64 ----
    // CG=8 x R=4: tile 128 rows x 64 cols, 782 blocks (round-6 proven config)
    gemm_rb<128, 64, 8, 4, true><<<(M + 127) / 128, 256, 0, stream>>>(
        x, Wenc, dinv, nullptr, nullptr, hs1h, M);
    gcn_agg1<<<(M + 3) / 4, 256, 0, stream>>>(
        hs1h, csr, cnt, dinv, benc, emb, ghalf, M, cap);

    // ---- layer 2: fused aggregate + decode (64 -> 128) ----
    // 32 nodes/block (4 waves x 8 nodes), 3125 blocks
    agg2_dec<<<(M + 31) / 32, 256, 0, stream>>>(
        ghalf, csr, cnt, dinv, Wdec, bdec, recon, M, cap);
}

// Round 9
// 271.031 us; speedup vs baseline: 2.3594x; 1.1558x over previous
//
#include <hip/hip_runtime.h>
#include <hip/hip_fp16.h>

// ---------------------------------------------------------------------------
// localAE: two GCNConv layers (128->64 encode, 64->128 decode), N=100000,
// E=1.6M.  out[n] = dinv[n] * (hs[n] + sum_{e: dst==n} hs[src_e]) + b
// where hs = (X @ W) * dinv[row],  dinv = rsqrt(1 + indegree).
//
// Round 11: (a) round-8 fusion reverted (agg2_dec serialized 8 gather chains
// per wave -> 98us vs 81 split; gather parallelism = wave count). (b) Both
// GEMMs moved to MFMA (mfma_f32_16x16x32_f16): three rounds of VALU-GEMM
// retiling pinned at 46-56us vs ~10us floor (LDS-issue + latency structural).
// A-operand: f32 global load + in-register cvt to fp16 (no extra pass, no
// new storage rounding). B: W transposed into LDS fp16 (row pad +8 -> 2-way
// bank conflict, free). Wave computes 16 rows x N: 16 MFMAs. f32 accumulate;
// adds ~2^-11-rel rounding on X,W only.
// ---------------------------------------------------------------------------

#define BSHIFT 7                      // 128 nodes per bucket
#define BNODES (1 << BSHIFT)
#define NB_LDS 1024                   // LDS histogram capacity (NB <= 1024)

typedef _Float16 half8 __attribute__((ext_vector_type(8)));
typedef float    f32x4 __attribute__((ext_vector_type(4)));

// P1: partition edges into buckets by dst>>BSHIFT, packed (src<<BSHIFT)|dloc.
// One global atomic per (block,bucket) instead of per edge (fabric-RMW wall).
__global__ __launch_bounds__(1024)
void part_kernel(const int* __restrict__ src, const int* __restrict__ dst,
                 int E, int NB, int* __restrict__ gcur, int* __restrict__ gbuf,
                 int BSTRIDE)
{
    __shared__ int hist[NB_LDS];
    __shared__ int bbase[NB_LDS];
    const int tid = threadIdx.x;
    for (int i = tid; i < NB; i += 1024) hist[i] = 0;
    __syncthreads();

    const int base = (blockIdx.x * 1024 + tid) * 4;
    int bk[4], lp[4], pk[4];
    int nv = 0;
    if (base + 4 <= E) {
        const int4 d4 = *reinterpret_cast<const int4*>(dst + base);
        const int4 s4 = *reinterpret_cast<const int4*>(src + base);
        nv = 4;
        #pragma unroll
        for (int k = 0; k < 4; ++k) {
            const int d = (&d4.x)[k];
            bk[k] = d >> BSHIFT;
            pk[k] = ((&s4.x)[k] << BSHIFT) | (d & (BNODES - 1));
            lp[k] = atomicAdd(&hist[bk[k]], 1);
        }
    } else {
        for (int k = 0; base + k < E && k < 4; ++k) {
            const int d = dst[base + k];
            bk[nv] = d >> BSHIFT;
            pk[nv] = (src[base + k] << BSHIFT) | (d & (BNODES - 1));
            lp[nv] = atomicAdd(&hist[bk[nv]], 1);
            ++nv;
        }
    }
    __syncthreads();
    for (int i = tid; i < NB; i += 1024) {
        const int c = hist[i];
        bbase[i] = c ? atomicAdd(&gcur[i], c) : 0;   // one device atomic per (block,bucket)
    }
    __syncthreads();
    for (int k = 0; k < nv; ++k) {
        const int pos = bbase[bk[k]] + lp[k];
        if (pos < BSTRIDE) gbuf[(size_t)bk[k] * BSTRIDE + pos] = pk[k];
    }
}

// P2: per bucket (128 nodes), slot edges into CSR rows via LDS cursors
// (zero fabric RMW); CSR writes confined to a 32KB region -> merge in L2.
// Degree count + dinv fused.
__global__ __launch_bounds__(256)
void csr_kernel(const int* __restrict__ gcur, const int* __restrict__ gbuf,
                int BSTRIDE, int* __restrict__ csr, int cap,
                int* __restrict__ cnt, float* __restrict__ dinv, int M)
{
    __shared__ int cur[BNODES];
    const int tid = threadIdx.x;
    const int b   = blockIdx.x;
    if (tid < BNODES) cur[tid] = 0;
    __syncthreads();

    int nb = gcur[b];
    if (nb > BSTRIDE) nb = BSTRIDE;
    const int* __restrict__ buf = gbuf + (size_t)b * BSTRIDE;
    const int n0 = b << BSHIFT;

    for (int i = tid; i < nb; i += 256) {
        const int p = buf[i];
        const int d = p & (BNODES - 1);
        const int s = p >> BSHIFT;
        const int lpos = atomicAdd(&cur[d], 1);        // LDS atomic
        if (lpos < cap) csr[(size_t)(n0 + d) * cap + lpos] = s;
    }
    __syncthreads();
    const int n = n0 + tid;
    if (tid < BNODES && n < M) {
        const int c = cur[tid];
        cnt[n]  = c;                                   // true in-degree
        dinv[n] = rsqrtf((float)c + 1.0f);             // +1 self-loop
    }
}

// MFMA GEMM: out[m,:] = (X[m,:] @ W) * dinv[m] (+ bias).
// Block = 4 waves; wave computes 16 rows x N via mfma_f32_16x16x32_f16.
// A: f32 global load + in-reg cvt (lane: row=lane&15, k=(lane>>4)*8+j).
// B: W transposed to LDS fp16 Wt[n][k], row pad +8 halves (2-way conflict).
// C/D: col=lane&15, row=(lane>>4)*4+reg (guide-verified mapping).
template<int K, int N, bool HOUT>
__global__ __launch_bounds__(256)
void gemm_mfma(const float* __restrict__ X, const float* __restrict__ W,
               const float* __restrict__ dinv, const float* __restrict__ bias,
               float* __restrict__ out, __half* __restrict__ outh, int M)
{
    constexpr int KP = K + 8;                  // padded LDS row, in fp16 units
    constexpr int NT = N / 16;                 // 16-col tiles
    constexpr int KC = K / 32;                 // 32-k chunks
    __shared__ _Float16 Wt[N * KP];

    const int tid = threadIdx.x;
    for (int i = tid; i < K * N; i += 256) {   // coalesced f32 read, transposed fp16 write
        const int k = i / N, n = i - k * N;
        Wt[n * KP + k] = (_Float16)W[i];
    }
    __syncthreads();

    const int wid  = tid >> 6;
    const int lane = tid & 63;
    const int row0 = (blockIdx.x * 4 + wid) * 16;
    const int rA   = lane & 15;
    const int kg   = lane >> 4;                // k-group 0..3

    int ar = row0 + rA;
    if (ar >= M) ar = M - 1;                   // clamp loads; stores guarded
    const float4* __restrict__ xr4 = reinterpret_cast<const float4*>(X + (size_t)ar * K);

    half8 afrag[KC];
    #pragma unroll
    for (int kc = 0; kc < KC; ++kc) {
        const float4 x0 = xr4[kc * 8 + kg * 2];
        const float4 x1 = xr4[kc * 8 + kg * 2 + 1];
        afrag[kc][0] = (_Float16)x0.x; afrag[kc][1] = (_Float16)x0.y;
        afrag[kc][2] = (_Float16)x0.z; afrag[kc][3] = (_Float16)x0.w;
        afrag[kc][4] = (_Float16)x1.x; afrag[kc][5] = (_Float16)x1.y;
        afrag[kc][6] = (_Float16)x1.z; afrag[kc][7] = (_Float16)x1.w;
    }

    f32x4 acc[NT];
    #pragma unroll
    for (int nt = 0; nt < NT; ++nt) acc[nt] = (f32x4){0.f, 0.f, 0.f, 0.f};

    #pragma unroll
    for (int nt = 0; nt < NT; ++nt) {
        #pragma unroll
        for (int kc = 0; kc < KC; ++kc) {
            const half8 bfrag =
                *reinterpret_cast<const half8*>(&Wt[(nt * 16 + rA) * KP + kc * 32 + kg * 8]);
            acc[nt] = __builtin_amdgcn_mfma_f32_16x16x32_f16(afrag[kc], bfrag, acc[nt], 0, 0, 0);
        }
    }

    // D: row = row0 + kg*4 + r, col = nt*16 + rA
    const int orow0 = row0 + kg * 4;
    #pragma unroll
    for (int nt = 0; nt < NT; ++nt) {
        const int col = nt * 16 + rA;
        #pragma unroll
        for (int r = 0; r < 4; ++r) {
            const int gr = orow0 + r;
            if (gr < M) {
                const float d = dinv[gr];
                if constexpr (HOUT) {
                    outh[(size_t)gr * N + col] = __float2half_rn(acc[nt][r] * d);
                } else {
                    out[(size_t)gr * N + col] = acc[nt][r] * d + bias[col];
                }
            }
        }
    }
}

// Wave-per-node gather aggregation over 64-dim fp16 rows (1 half/lane,
// 128B/wave-gather = one cache line). f32 accumulate. Edge-index loads are
// wave-uniform (n pinned to SGPR) -> scalar loads. Unroll 16 ~ avg degree.
//  FIRST=true : hsh = hs1;  emb[n] = acc*dinv[n] + bias (f32 out)
//               and ghalf[n] = emb[n]*dinv[n] (fp16 out, feeds agg2)
//  FIRST=false: hsh = g;    out[n] = acc (f32, feeds decode GEMM)
template<bool FIRST>
__global__ __launch_bounds__(256)
void gcn_agg(const __half* __restrict__ hsh, const int* __restrict__ csr,
             const int* __restrict__ cnt, const float* __restrict__ dinv,
             const float* __restrict__ bias, float* __restrict__ outf,
             __half* __restrict__ outh, int M, int cap)
{
    const int lane = threadIdx.x & 63;
    int n = (blockIdx.x * 256 + threadIdx.x) >> 6;
    if (n >= M) return;
    n = __builtin_amdgcn_readfirstlane(n);
    int deg = cnt[n];
    if (deg > cap) deg = cap;
    const int* __restrict__ lst = csr + (size_t)n * cap;

    float acc = __half2float(hsh[(size_t)n * 64 + lane]);

    int j = 0;
    for (; j + 16 <= deg; j += 16) {
        int   s[16];
        float v[16];
        #pragma unroll
        for (int k = 0; k < 16; ++k) s[k] = lst[j + k];
        #pragma unroll
        for (int k = 0; k < 16; ++k) v[k] = __half2float(hsh[(size_t)s[k] * 64 + lane]);
        float t = 0.f;
        #pragma unroll
        for (int k = 0; k < 16; ++k) t += v[k];
        acc += t;
    }
    for (; j + 4 <= deg; j += 4) {
        const int s0 = lst[j], s1 = lst[j + 1], s2 = lst[j + 2], s3 = lst[j + 3];
        const float v0 = __half2float(hsh[(size_t)s0 * 64 + lane]);
        const float v1 = __half2float(hsh[(size_t)s1 * 64 + lane]);
        const float v2 = __half2float(hsh[(size_t)s2 * 64 + lane]);
        const float v3 = __half2float(hsh[(size_t)s3 * 64 + lane]);
        acc += (v0 + v1) + (v2 + v3);
    }
    for (; j < deg; ++j) acc += __half2float(hsh[(size_t)lst[j] * 64 + lane]);

    if constexpr (FIRST) {
        const float dv = dinv[n];
        const float e  = acc * dv + bias[lane];
        outf[(size_t)n * 64 + lane] = e;                       // emb (f32 output)
        outh[(size_t)n * 64 + lane] = __float2half_rn(e * dv); // g = emb*dinv (fp16)
    } else {
        outf[(size_t)n * 64 + lane] = acc;                     // agg2 (f32)
    }
}

extern "C" void kernel_launch(void* const* d_in, const int* in_sizes, int n_in,
                              void* d_out, int out_size, void* d_ws, size_t ws_size,
                              hipStream_t stream)
{
    const float* x    = (const float*)d_in[0];   // [M,128]
    const int*   ei   = (const int*)  d_in[1];   // [2,E]
    const float* Wenc = (const float*)d_in[2];   // [128,64]
    const float* benc = (const float*)d_in[3];   // [64]
    const float* Wdec = (const float*)d_in[4];   // [64,128]
    const float* bdec = (const float*)d_in[5];   // [128]

    const int M = in_sizes[0] / 128;             // 100000
    const int E = in_sizes[1] / 2;               // 1600000
    const int* src  = ei;
    const int* dstv = ei + E;

    float* emb   = (float*)d_out;                       // [M,64]
    float* recon = (float*)d_out + (size_t)M * 64;      // [M,128]

    const int NB      = (M + BNODES - 1) >> BSHIFT;     // 782 buckets
    const int BSTRIDE = 3072;                           // mean 2046, +22 sigma

    // workspace layout (int units):
    //   [0,       M*32)    hs1h  (layer-1 pre-agg, fp16, M*64 halves)
    //   [M*32,    M*64)    ghalf (g = emb*dinv, fp16, M*64 halves)
    //   [M*64,    M*128)   gbuf (P1 output, 2.4M ints) UNION agg2 (f32 M*64)
    //   [M*128,   M*129)   cnt  (in-degree)
    //   [M*129,   M*130)   dinv (f32)
    //   [M*130,   +1024)   gcur (bucket counters, padded)
    //   [M*130+1024, ...)  csr  (M*cap)
    __half* hs1h  = (__half*)d_ws;
    __half* ghalf = (__half*)((int*)d_ws + (size_t)M * 32);
    int*    gbuf  = (int*)d_ws + (size_t)M * 64;
    float*  agg2  = (float*)((int*)d_ws + (size_t)M * 64);
    int*    cnt   = (int*)d_ws + (size_t)M * 128;
    float*  dinv  = (float*)((int*)d_ws + (size_t)M * 129);
    int*    gcur  = (int*)d_ws + (size_t)M * 130;
    int*    csr   = (int*)d_ws + (size_t)M * 130 + 1024;

    const size_t used = ((size_t)M * 130 + 1024) * 4;
    int cap = 64;                                        // Poisson(16): P(deg>64) ~ 1e-50
    const size_t avail = (ws_size > used) ? (ws_size - used) / ((size_t)M * 4) : 0;
    if ((size_t)cap > avail) cap = (int)avail;

    hipMemsetAsync(gcur, 0, 1024 * sizeof(int), stream);

    // ---- CSR build: partition (4096 edges/block) then per-bucket slotting ----
    part_kernel<<<(E + 4095) / 4096, 1024, 0, stream>>>(src, dstv, E, NB, gcur, gbuf, BSTRIDE);
    csr_kernel<<<NB, 256, 0, stream>>>(gcur, gbuf, BSTRIDE, csr, cap, cnt, dinv, M);

    const int aggBlocks = (M + 3) / 4;   // 4 waves (nodes) per 256-thread block

    // ---- layer 1: encode 128 -> 64 (MFMA, 64 rows/block -> 1563 blocks) ----
    gemm_mfma<128, 64, true><<<(M + 63) / 64, 256, 0, stream>>>(
        x, Wenc, dinv, nullptr, nullptr, hs1h, M);
    gcn_agg<true><<<aggBlocks, 256, 0, stream>>>(
        hs1h, csr, cnt, dinv, benc, emb, ghalf, M, cap);

    // ---- layer 2: decode 64 -> 128 (aggregate in 64-dim, then MFMA GEMM) ----
    gcn_agg<false><<<aggBlocks, 256, 0, stream>>>(
        ghalf, csr, cnt, nullptr, nullptr, agg2, nullptr, M, cap);
    gemm_mfma<64, 128, false><<<(M + 63) / 64, 256, 0, stream>>>(
        agg2, Wdec, dinv, bdec, recon, nullptr, M);
}